// Round 3
// baseline (5215.570 us; speedup 1.0000x reference)
//
#include <hip/hip_runtime.h>

#define BATCH 4
#define NPTS  16384
#define SPTS  4096
#define C1    128
#define C2    256
#define CIN   384
#define H1    256
#define H2    128
#define MROWS (BATCH * NPTS)   // 65536

#define CHUNK  512
#define NCHUNK (SPTS / CHUNK)  // 8

// ---------------------------------------------------------------------------
// KNN phase 1: per-chunk top-3. FROZEN ARITHMETIC (verified passing,
// absmax 0.03125):
//   sq  = fma(z,z, fma(x,x, y*y))
//   dot = fma(qz,pz, fma(qy,py, qx*px))
//   t1  = sq1 + sq2        (plain)
//   d2  = fma(-2, dot, t1)
// Strict-< insertion, global candidate index.
// ---------------------------------------------------------------------------
__global__ __launch_bounds__(256) void knn_part_kernel(
    const float* __restrict__ xyz1, const float* __restrict__ xyz2,
    float* __restrict__ pd, int* __restrict__ pi) {
#pragma clang fp contract(off)
  __shared__ float4 pts[CHUNK];  // 8 KB
  const int b = blockIdx.z;
  const int chunk = blockIdx.y;
  const int c0 = chunk * CHUNK;
  const float* src = xyz2 + ((size_t)b * SPTS + c0) * 3;
  for (int i = threadIdx.x; i < CHUNK; i += 256) {
    float px = src[i * 3 + 0], py = src[i * 3 + 1], pz = src[i * 3 + 2];
    float s = fmaf(pz, pz, fmaf(px, px, py * py));
    pts[i] = make_float4(px, py, pz, s);
  }
  __syncthreads();

  const int n = blockIdx.x * 256 + threadIdx.x;
  const size_t row = (size_t)b * NPTS + n;
  const float qx = xyz1[row * 3 + 0], qy = xyz1[row * 3 + 1], qz = xyz1[row * 3 + 2];
  const float sq1 = fmaf(qz, qz, fmaf(qx, qx, qy * qy));

  float b0 = 1e30f, b1v = 1e30f, b2v = 1e30f;
  int i0 = 0, i1 = 0, i2 = 0;
  for (int s = 0; s < CHUNK; ++s) {
    float4 p = pts[s];
    float dot = fmaf(qz, p.z, fmaf(qy, p.y, qx * p.x));
    float t1 = sq1 + p.w;
    float d = fmaf(-2.0f, dot, t1);
    if (d < b2v) {
      int gi = c0 + s;
      if (d < b1v) {
        b2v = b1v; i2 = i1;
        if (d < b0) { b1v = b0; i1 = i0; b0 = d; i0 = gi; }
        else        { b1v = d;  i1 = gi; }
      } else { b2v = d; i2 = gi; }
    }
  }
  const size_t o = (row * NCHUNK + chunk) * 3;
  pd[o + 0] = b0;  pd[o + 1] = b1v; pd[o + 2] = b2v;
  pi[o + 0] = i0;  pi[o + 1] = i1;  pi[o + 2] = i2;
}

// ---------------------------------------------------------------------------
// KNN phase 2: merge 8 partial top-3s (frozen).
// ---------------------------------------------------------------------------
__global__ __launch_bounds__(256) void knn_merge_kernel(
    const float* __restrict__ pd, const int* __restrict__ pi,
    int* __restrict__ idx3, float* __restrict__ w3) {
#pragma clang fp contract(off)
  const size_t row = (size_t)blockIdx.x * 256 + threadIdx.x;
  const size_t base = row * (NCHUNK * 3);
  float b0 = 1e30f, b1v = 1e30f, b2v = 1e30f;
  int i0 = 0, i1 = 0, i2 = 0;
#pragma unroll
  for (int k = 0; k < NCHUNK * 3; ++k) {
    float d = pd[base + k];
    int gi = pi[base + k];
    if (d < b2v) {
      if (d < b1v) {
        b2v = b1v; i2 = i1;
        if (d < b0) { b1v = b0; i1 = i0; b0 = d; i0 = gi; }
        else        { b1v = d;  i1 = gi; }
      } else { b2v = d; i2 = gi; }
    }
  }
  float r0 = 1.0f / (b0 + 1e-8f);
  float r1 = 1.0f / (b1v + 1e-8f);
  float r2 = 1.0f / (b2v + 1e-8f);
  float rs = (r0 + r1) + r2;
  idx3[row * 3 + 0] = i0; idx3[row * 3 + 1] = i1; idx3[row * 3 + 2] = i2;
  w3[row * 3 + 0] = r0 / rs;
  w3[row * 3 + 1] = r1 / rs;
  w3[row * 3 + 2] = r2 / rs;
}

// ---------------------------------------------------------------------------
// GEMMs: 128x128 tile, BK=32, 512 threads (8 waves), 4x8 microtile.
// Double-buffered LDS (64 KB), issue-early loads, ONE barrier per tile.
// Per-thread state halved vs the spilling round-2 version: acc 32 + staging
// 8 float4 = 32 -> ~120 VGPR. __launch_bounds__(512,3) caps the allocator
// (~170) so a 256-VGPR spill explosion cannot recur.
// Loader map ar=t&127, ks=(t>>7)*8: all LDS stores 2-way bank (free),
// A-frag reads broadcast, B-frag reads 2-way.
// K-accumulation: c ascending 0..31, tiles ascending — bit-identical fmaf
// chain per output to the round-1 verified kernel.
// ---------------------------------------------------------------------------
#define BM 128
#define BN 128
#define BK 32

__global__ __launch_bounds__(512, 3) void gemm1_kernel(
    const float* __restrict__ features2, const float* __restrict__ features1,
    const int* __restrict__ idx3, const float* __restrict__ w3,
    const float* __restrict__ W1, const float* __restrict__ b1,
    float* __restrict__ h1) {
  __shared__ float As[2][BK][BM];  // 32 KB
  __shared__ float Bs[2][BK][BN];  // 32 KB
  const int t = threadIdx.x;
  const int m0 = blockIdx.x * BM;
  const int n0 = blockIdx.y * BN;
  const int tx = t & 15, ty = t >> 4;   // compute: 32(m) x 16(n) threads

  const int ar = t & 127;           // A loader: row 0..127
  const int ks = (t >> 7) * 8;      // k-octet 0,8,16,24
  const size_t arow = m0 + ar;
  const int ab = (int)(arow >> 14);
  const float* f2 = features2 + (size_t)ab * SPTS * C2;
  const float* p0 = f2 + (size_t)idx3[arow * 3 + 0] * C2;
  const float* p1 = f2 + (size_t)idx3[arow * 3 + 1] * C2;
  const float* p2 = f2 + (size_t)idx3[arow * 3 + 2] * C2;
  const float w0 = w3[arow * 3 + 0];
  const float w1 = w3[arow * 3 + 1];
  const float w2 = w3[arow * 3 + 2];
  const float* f1row = features1 + arow * C1;

  const int bn = t & 127;           // B loader: col 0..127
  const int bks = (t >> 7) * 8;
  const float* wbase = W1 + (size_t)(n0 + bn) * CIN;

  float4 a0[2], a1[2], a2[2], bstg[2];
  float acc[4][8] = {};

  auto load_tile = [&](int k0) {
    if (k0 < C2) {
#pragma unroll
      for (int q = 0; q < 2; ++q) {
        int col = k0 + ks + q * 4;
        a0[q] = *(const float4*)&p0[col];
        a1[q] = *(const float4*)&p1[col];
        a2[q] = *(const float4*)&p2[col];
      }
    } else {
#pragma unroll
      for (int q = 0; q < 2; ++q)
        a0[q] = *(const float4*)&f1row[k0 + ks + q * 4 - C2];
    }
#pragma unroll
    for (int q = 0; q < 2; ++q)
      bstg[q] = *(const float4*)&wbase[k0 + bks + q * 4];
  };

  auto store_tile = [&](int buf, int k0) {
    if (k0 < C2) {
#pragma unroll
      for (int q = 0; q < 2; ++q) {
        As[buf][ks + q * 4 + 0][ar] = w0 * a0[q].x + w1 * a1[q].x + w2 * a2[q].x;
        As[buf][ks + q * 4 + 1][ar] = w0 * a0[q].y + w1 * a1[q].y + w2 * a2[q].y;
        As[buf][ks + q * 4 + 2][ar] = w0 * a0[q].z + w1 * a1[q].z + w2 * a2[q].z;
        As[buf][ks + q * 4 + 3][ar] = w0 * a0[q].w + w1 * a1[q].w + w2 * a2[q].w;
      }
    } else {
#pragma unroll
      for (int q = 0; q < 2; ++q) {
        As[buf][ks + q * 4 + 0][ar] = a0[q].x;
        As[buf][ks + q * 4 + 1][ar] = a0[q].y;
        As[buf][ks + q * 4 + 2][ar] = a0[q].z;
        As[buf][ks + q * 4 + 3][ar] = a0[q].w;
      }
    }
#pragma unroll
    for (int q = 0; q < 2; ++q) {
      Bs[buf][bks + q * 4 + 0][bn] = bstg[q].x;
      Bs[buf][bks + q * 4 + 1][bn] = bstg[q].y;
      Bs[buf][bks + q * 4 + 2][bn] = bstg[q].z;
      Bs[buf][bks + q * 4 + 3][bn] = bstg[q].w;
    }
  };

  load_tile(0);
  store_tile(0, 0);
  __syncthreads();
  int cur = 0;
  for (int kt = 0; kt < CIN / BK; ++kt) {
    const int k0n = (kt + 1) * BK;
    if (k0n < CIN) load_tile(k0n);   // issue-early: latency hides under FMA
#pragma unroll
    for (int c = 0; c < BK; ++c) {
      float4 av  = *(const float4*)&As[cur][c][ty * 4];
      float4 bv0 = *(const float4*)&Bs[cur][c][tx * 4];
      float4 bv1 = *(const float4*)&Bs[cur][c][64 + tx * 4];
      float aa[4] = {av.x, av.y, av.z, av.w};
      float bb[8] = {bv0.x, bv0.y, bv0.z, bv0.w, bv1.x, bv1.y, bv1.z, bv1.w};
#pragma unroll
      for (int i = 0; i < 4; ++i)
#pragma unroll
        for (int j = 0; j < 8; ++j) acc[i][j] = fmaf(aa[i], bb[j], acc[i][j]);
    }
    if (k0n < CIN) store_tile(cur ^ 1, k0n);
    __syncthreads();
    cur ^= 1;
  }

  float4 bias0 = *(const float4*)&b1[n0 + tx * 4];
  float4 bias1 = *(const float4*)&b1[n0 + 64 + tx * 4];
#pragma unroll
  for (int i = 0; i < 4; ++i) {
    size_t row = m0 + ty * 4 + i;
    *(float4*)&h1[row * H1 + n0 + tx * 4] =
        make_float4(acc[i][0] + bias0.x, acc[i][1] + bias0.y,
                    acc[i][2] + bias0.z, acc[i][3] + bias0.w);
    *(float4*)&h1[row * H1 + n0 + 64 + tx * 4] =
        make_float4(acc[i][4] + bias1.x, acc[i][5] + bias1.y,
                    acc[i][6] + bias1.z, acc[i][7] + bias1.w);
  }
}

__global__ __launch_bounds__(512, 3) void gemm2_kernel(
    const float* __restrict__ h1, const float* __restrict__ scale1,
    const float* __restrict__ shift1, const float* __restrict__ W2,
    const float* __restrict__ b2, float* __restrict__ h2) {
  __shared__ float As[2][BK][BM];
  __shared__ float Bs[2][BK][BN];
  const int t = threadIdx.x;
  const int m0 = blockIdx.x * BM;
  const int n0 = blockIdx.y * BN;
  const int tx = t & 15, ty = t >> 4;

  const int ar = t & 127;
  const int ks = (t >> 7) * 8;
  const size_t arow = m0 + ar;
  const float* hrow = h1 + arow * H1;

  const int bn = t & 127;
  const int bks = (t >> 7) * 8;
  const float* wbase = W2 + (size_t)(n0 + bn) * H1;

  float4 vstg[2], scstg[2], shstg[2], bstg[2];
  float acc[4][8] = {};

  auto load_tile = [&](int k0) {
#pragma unroll
    for (int q = 0; q < 2; ++q) {
      int col = k0 + ks + q * 4;
      vstg[q]  = *(const float4*)&hrow[col];
      scstg[q] = *(const float4*)&scale1[col];
      shstg[q] = *(const float4*)&shift1[col];
    }
#pragma unroll
    for (int q = 0; q < 2; ++q)
      bstg[q] = *(const float4*)&wbase[k0 + bks + q * 4];
  };

  auto store_tile = [&](int buf, int k0) {
#pragma unroll
    for (int q = 0; q < 2; ++q) {
      As[buf][ks + q * 4 + 0][ar] = fmaxf(fmaf(vstg[q].x, scstg[q].x, shstg[q].x), 0.0f);
      As[buf][ks + q * 4 + 1][ar] = fmaxf(fmaf(vstg[q].y, scstg[q].y, shstg[q].y), 0.0f);
      As[buf][ks + q * 4 + 2][ar] = fmaxf(fmaf(vstg[q].z, scstg[q].z, shstg[q].z), 0.0f);
      As[buf][ks + q * 4 + 3][ar] = fmaxf(fmaf(vstg[q].w, scstg[q].w, shstg[q].w), 0.0f);
    }
#pragma unroll
    for (int q = 0; q < 2; ++q) {
      Bs[buf][bks + q * 4 + 0][bn] = bstg[q].x;
      Bs[buf][bks + q * 4 + 1][bn] = bstg[q].y;
      Bs[buf][bks + q * 4 + 2][bn] = bstg[q].z;
      Bs[buf][bks + q * 4 + 3][bn] = bstg[q].w;
    }
  };

  load_tile(0);
  store_tile(0, 0);
  __syncthreads();
  int cur = 0;
  for (int kt = 0; kt < H1 / BK; ++kt) {
    const int k0n = (kt + 1) * BK;
    if (k0n < H1) load_tile(k0n);
#pragma unroll
    for (int c = 0; c < BK; ++c) {
      float4 av  = *(const float4*)&As[cur][c][ty * 4];
      float4 bv0 = *(const float4*)&Bs[cur][c][tx * 4];
      float4 bv1 = *(const float4*)&Bs[cur][c][64 + tx * 4];
      float aa[4] = {av.x, av.y, av.z, av.w};
      float bb[8] = {bv0.x, bv0.y, bv0.z, bv0.w, bv1.x, bv1.y, bv1.z, bv1.w};
#pragma unroll
      for (int i = 0; i < 4; ++i)
#pragma unroll
        for (int j = 0; j < 8; ++j) acc[i][j] = fmaf(aa[i], bb[j], acc[i][j]);
    }
    if (k0n < H1) store_tile(cur ^ 1, k0n);
    __syncthreads();
    cur ^= 1;
  }

  float4 bias0 = *(const float4*)&b2[n0 + tx * 4];
  float4 bias1 = *(const float4*)&b2[n0 + 64 + tx * 4];
#pragma unroll
  for (int i = 0; i < 4; ++i) {
    size_t row = m0 + ty * 4 + i;
    *(float4*)&h2[row * H2 + n0 + tx * 4] =
        make_float4(acc[i][0] + bias0.x, acc[i][1] + bias0.y,
                    acc[i][2] + bias0.z, acc[i][3] + bias0.w);
    *(float4*)&h2[row * H2 + n0 + 64 + tx * 4] =
        make_float4(acc[i][4] + bias1.x, acc[i][5] + bias1.y,
                    acc[i][6] + bias1.z, acc[i][7] + bias1.w);
  }
}

// ---------------------------------------------------------------------------
// BN stats, two-stage (no atomics). Partials overlay DEAD storage.
// ---------------------------------------------------------------------------
__global__ __launch_bounds__(256) void colstats_part_kernel(
    const float* __restrict__ h, double* __restrict__ psum,
    double* __restrict__ psq, int C, int logC, int rowsPerBlock) {
  const int t = threadIdx.x;
  const int G = 256 >> logC;       // 1 for C=256, 2 for C=128
  const int c = t & (C - 1);
  const int g = t >> logC;
  const size_t row0 = (size_t)blockIdx.x * rowsPerBlock;
  double s = 0.0, s2 = 0.0;
  for (int r = g; r < rowsPerBlock; r += G) {
    double v = (double)h[(row0 + r) * C + c];
    s += v;
    s2 += v * v;
  }
  const size_t o = (size_t)(blockIdx.x * G + g) * C + c;
  psum[o] = s;
  psq[o] = s2;
}

__global__ __launch_bounds__(256) void colstats_reduce_kernel(
    const double* __restrict__ psum, const double* __restrict__ psq,
    int C, int P, double* __restrict__ sum, double* __restrict__ sumsq) {
  const int t = threadIdx.x;
  const int c = blockIdx.x * 64 + (t & 63);
  const int j = t >> 6;  // 0..3
  double s = 0.0, s2 = 0.0;
  for (int p = j; p < P; p += 4) {
    s += psum[(size_t)p * C + c];
    s2 += psq[(size_t)p * C + c];
  }
  __shared__ double red[2][4][64];
  red[0][j][t & 63] = s;
  red[1][j][t & 63] = s2;
  __syncthreads();
  if (j == 0) {
    double fs = red[0][0][t] + red[0][1][t] + red[0][2][t] + red[0][3][t];
    double fq = red[1][0][t] + red[1][1][t] + red[1][2][t] + red[1][3][t];
    sum[c] = fs;
    sumsq[c] = fq;
  }
}

__global__ void finalize_kernel(const double* __restrict__ sum,
                                const double* __restrict__ sumsq,
                                const float* __restrict__ g,
                                const float* __restrict__ be,
                                float* __restrict__ scale,
                                float* __restrict__ shift) {
  const int c = threadIdx.x;
  const double invM = 1.0 / (double)MROWS;
  double mean = sum[c] * invM;
  double var = sumsq[c] * invM - mean * mean;
  double sc = (double)g[c] / sqrt(var + 1e-5);
  scale[c] = (float)sc;
  shift[c] = (float)((double)be[c] - mean * sc);
}

// In-place: io = relu(io*scale2 + shift2), float4-vectorized.
__global__ __launch_bounds__(256) void final_kernel(
    float* __restrict__ io, const float* __restrict__ scale2,
    const float* __restrict__ shift2) {
  const size_t i = (size_t)blockIdx.x * 256 + threadIdx.x;
  const int col4 = (int)(i & 31);
  float4 h = ((float4*)io)[i];
  float4 sc = ((const float4*)scale2)[col4];
  float4 sh = ((const float4*)shift2)[col4];
  float4 o;
  o.x = fmaxf(fmaf(h.x, sc.x, sh.x), 0.0f);
  o.y = fmaxf(fmaf(h.y, sc.y, sh.y), 0.0f);
  o.z = fmaxf(fmaf(h.z, sc.z, sh.z), 0.0f);
  o.w = fmaxf(fmaf(h.w, sc.w, sh.w), 0.0f);
  ((float4*)io)[i] = o;
}

extern "C" void kernel_launch(void* const* d_in, const int* in_sizes, int n_in,
                              void* d_out, int out_size, void* d_ws,
                              size_t ws_size, hipStream_t stream) {
  const float* xyz1      = (const float*)d_in[0];
  const float* xyz2      = (const float*)d_in[1];
  const float* features1 = (const float*)d_in[2];
  const float* features2 = (const float*)d_in[3];
  const float* W1  = (const float*)d_in[4];
  const float* b1  = (const float*)d_in[5];
  const float* g1  = (const float*)d_in[6];
  const float* be1 = (const float*)d_in[7];
  const float* W2  = (const float*)d_in[8];
  const float* b2  = (const float*)d_in[9];
  const float* g2  = (const float*)d_in[10];
  const float* be2 = (const float*)d_in[11];
  float* out = (float*)d_out;

  // Workspace (~66 MB): h1 | w3 | idx3 | fp64 sums | scale/shift.
  // KNN partials (pd 6.3MB + pi 6.3MB) OVERLAY the h1 region: consumed by
  // knn_merge before gemm1 writes h1.
  char* wsb   = (char*)d_ws;
  float* h1   = (float*)wsb;                               // 64 MB
  float* w3   = (float*)(wsb + (size_t)MROWS * H1 * 4);
  int* idx3   = (int*)(wsb + (size_t)MROWS * H1 * 4 + (size_t)MROWS * 3 * 4);
  double* sums = (double*)((char*)idx3 + (size_t)MROWS * 3 * 4);
  double* sum1 = sums;
  double* sq1s = sums + 256;
  double* sum2 = sums + 512;
  double* sq2s = sums + 640;
  float* ss    = (float*)(sums + 768);
  float* scale1 = ss;
  float* shift1 = ss + 256;
  float* scale2 = ss + 512;
  float* shift2 = ss + 640;

  float* pd = h1;                                  // 6.3 MB overlay
  int*   pi = (int*)(h1 + (size_t)MROWS * NCHUNK * 3);  // next 6.3 MB

  // BN-stats partials overlay dead buffers:
  //  h1 stats (before gemm2 writes out): partials in d_out (4 MB of 32 MB)
  //  out stats (after gemm2, h1 dead):   partials in h1    (4 MB of 64 MB)
  double* psum1 = (double*)out;
  double* psq1  = psum1 + (size_t)1024 * H1;       // P1 = 1024
  double* psum2 = (double*)h1;
  double* psq2  = psum2 + (size_t)2048 * H2;       // P2 = 1024*2 groups

  knn_part_kernel<<<dim3(NPTS / 256, NCHUNK, BATCH), 256, 0, stream>>>(
      xyz1, xyz2, pd, pi);
  knn_merge_kernel<<<MROWS / 256, 256, 0, stream>>>(pd, pi, idx3, w3);
  gemm1_kernel<<<dim3(MROWS / BM, H1 / BN), 512, 0, stream>>>(
      features2, features1, idx3, w3, W1, b1, h1);
  colstats_part_kernel<<<1024, 256, 0, stream>>>(h1, psum1, psq1, H1, 8,
                                                 MROWS / 1024);
  colstats_reduce_kernel<<<H1 / 64, 256, 0, stream>>>(psum1, psq1, H1, 1024,
                                                      sum1, sq1s);
  finalize_kernel<<<1, H1, 0, stream>>>(sum1, sq1s, g1, be1, scale1, shift1);
  gemm2_kernel<<<dim3(MROWS / BM, H2 / BN), 512, 0, stream>>>(h1, scale1, shift1,
                                                              W2, b2, out);
  colstats_part_kernel<<<1024, 256, 0, stream>>>(out, psum2, psq2, H2, 7,
                                                 MROWS / 1024);
  colstats_reduce_kernel<<<H2 / 64, 256, 0, stream>>>(psum2, psq2, H2, 2048,
                                                      sum2, sq2s);
  finalize_kernel<<<1, H2, 0, stream>>>(sum2, sq2s, g2, be2, scale2, shift2);
  final_kernel<<<(MROWS * H2 / 4) / 256, 256, 0, stream>>>(out, scale2, shift2);
}

// Round 4
// 780.957 us; speedup vs baseline: 6.6784x; 6.6784x over previous
//
#include <hip/hip_runtime.h>

#define BATCH 4
#define NPTS  16384
#define SPTS  4096
#define C1    128
#define C2    256
#define CIN   384
#define H1    256
#define H2    128
#define MROWS (BATCH * NPTS)   // 65536

#define CHUNK  512
#define NCHUNK (SPTS / CHUNK)  // 8

// ---------------------------------------------------------------------------
// KNN phase 1: per-chunk top-3. FROZEN ARITHMETIC (verified passing,
// absmax 0.03125).
// ---------------------------------------------------------------------------
__global__ __launch_bounds__(256) void knn_part_kernel(
    const float* __restrict__ xyz1, const float* __restrict__ xyz2,
    float* __restrict__ pd, int* __restrict__ pi) {
#pragma clang fp contract(off)
  __shared__ float4 pts[CHUNK];  // 8 KB
  const int b = blockIdx.z;
  const int chunk = blockIdx.y;
  const int c0 = chunk * CHUNK;
  const float* src = xyz2 + ((size_t)b * SPTS + c0) * 3;
  for (int i = threadIdx.x; i < CHUNK; i += 256) {
    float px = src[i * 3 + 0], py = src[i * 3 + 1], pz = src[i * 3 + 2];
    float s = fmaf(pz, pz, fmaf(px, px, py * py));
    pts[i] = make_float4(px, py, pz, s);
  }
  __syncthreads();

  const int n = blockIdx.x * 256 + threadIdx.x;
  const size_t row = (size_t)b * NPTS + n;
  const float qx = xyz1[row * 3 + 0], qy = xyz1[row * 3 + 1], qz = xyz1[row * 3 + 2];
  const float sq1 = fmaf(qz, qz, fmaf(qx, qx, qy * qy));

  float b0 = 1e30f, b1v = 1e30f, b2v = 1e30f;
  int i0 = 0, i1 = 0, i2 = 0;
  for (int s = 0; s < CHUNK; ++s) {
    float4 p = pts[s];
    float dot = fmaf(qz, p.z, fmaf(qy, p.y, qx * p.x));
    float t1 = sq1 + p.w;
    float d = fmaf(-2.0f, dot, t1);
    if (d < b2v) {
      int gi = c0 + s;
      if (d < b1v) {
        b2v = b1v; i2 = i1;
        if (d < b0) { b1v = b0; i1 = i0; b0 = d; i0 = gi; }
        else        { b1v = d;  i1 = gi; }
      } else { b2v = d; i2 = gi; }
    }
  }
  const size_t o = (row * NCHUNK + chunk) * 3;
  pd[o + 0] = b0;  pd[o + 1] = b1v; pd[o + 2] = b2v;
  pi[o + 0] = i0;  pi[o + 1] = i1;  pi[o + 2] = i2;
}

// ---------------------------------------------------------------------------
// KNN phase 2: merge 8 partial top-3s (frozen).
// ---------------------------------------------------------------------------
__global__ __launch_bounds__(256) void knn_merge_kernel(
    const float* __restrict__ pd, const int* __restrict__ pi,
    int* __restrict__ idx3, float* __restrict__ w3) {
#pragma clang fp contract(off)
  const size_t row = (size_t)blockIdx.x * 256 + threadIdx.x;
  const size_t base = row * (NCHUNK * 3);
  float b0 = 1e30f, b1v = 1e30f, b2v = 1e30f;
  int i0 = 0, i1 = 0, i2 = 0;
#pragma unroll
  for (int k = 0; k < NCHUNK * 3; ++k) {
    float d = pd[base + k];
    int gi = pi[base + k];
    if (d < b2v) {
      if (d < b1v) {
        b2v = b1v; i2 = i1;
        if (d < b0) { b1v = b0; i1 = i0; b0 = d; i0 = gi; }
        else        { b1v = d;  i1 = gi; }
      } else { b2v = d; i2 = gi; }
    }
  }
  float r0 = 1.0f / (b0 + 1e-8f);
  float r1 = 1.0f / (b1v + 1e-8f);
  float r2 = 1.0f / (b2v + 1e-8f);
  float rs = (r0 + r1) + r2;
  idx3[row * 3 + 0] = i0; idx3[row * 3 + 1] = i1; idx3[row * 3 + 2] = i2;
  w3[row * 3 + 0] = r0 / rs;
  w3[row * 3 + 1] = r1 / rs;
  w3[row * 3 + 2] = r2 / rs;
}

// ---------------------------------------------------------------------------
// GEMMs: 128x128 tile, BK=32, 512 threads, 4x8 microtile. SINGLE-buffer LDS
// (32 KB, R1's verified memory structure) + issue-early prefetch of tile t+1
// into INDIVIDUALLY NAMED float4 regs (no arrays, no lambdas — R2/R3's
// scratch demotion came from addressable aggregates; WRITE_SIZE 7.4GB was
// scratch, not spill). Loads issue after the post-store barrier, s_waitcnt
// lands at the NEXT iteration's LDS store -> ~900cy gather latency hides
// under ~4096cy of FMA. LDS stores 2-way bank (free), 0 conflicts (R3 PMC).
// K-accumulation: c ascending, tiles ascending — identical fmaf chain to the
// verified kernels.
// ---------------------------------------------------------------------------
#define BM 128
#define BN 128
#define BK 32

__global__ __launch_bounds__(512) void gemm1_kernel(
    const float* __restrict__ features2, const float* __restrict__ features1,
    const int* __restrict__ idx3, const float* __restrict__ w3,
    const float* __restrict__ W1, const float* __restrict__ b1,
    float* __restrict__ h1) {
  __shared__ float As[BK][BM];  // 16 KB
  __shared__ float Bs[BK][BN];  // 16 KB
  const int t = threadIdx.x;
  const int m0 = blockIdx.x * BM;
  const int n0 = blockIdx.y * BN;
  const int tx = t & 15, ty = t >> 4;   // compute: 32(m-quads) x 16(n-quads)

  const int ar = t & 127;           // A loader: row 0..127
  const int ks = (t >> 7) * 8;      // k-octet 0,8,16,24
  const size_t arow = m0 + ar;
  const int ab = (int)(arow >> 14);
  const float* f2 = features2 + (size_t)ab * SPTS * C2;
  const float* p0 = f2 + (size_t)idx3[arow * 3 + 0] * C2;
  const float* p1 = f2 + (size_t)idx3[arow * 3 + 1] * C2;
  const float* p2 = f2 + (size_t)idx3[arow * 3 + 2] * C2;
  const float w0 = w3[arow * 3 + 0];
  const float w1 = w3[arow * 3 + 1];
  const float w2 = w3[arow * 3 + 2];
  const float* f1row = features1 + arow * C1;

  const int bn = t & 127;           // B loader: col 0..127
  const int bks = (t >> 7) * 8;
  const float* wbase = W1 + (size_t)(n0 + bn) * CIN;

  // Named staging regs (NOT arrays — keeps them in VGPRs).
  float4 a00, a01, a10, a11, a20, a21, bw0, bw1;

  // Prologue: tile 0 (k0 = 0 < C2).
  a00 = *(const float4*)&p0[ks + 0];
  a01 = *(const float4*)&p0[ks + 4];
  a10 = *(const float4*)&p1[ks + 0];
  a11 = *(const float4*)&p1[ks + 4];
  a20 = *(const float4*)&p2[ks + 0];
  a21 = *(const float4*)&p2[ks + 4];
  bw0 = *(const float4*)&wbase[bks + 0];
  bw1 = *(const float4*)&wbase[bks + 4];

  float acc[4][8] = {};

  for (int kt = 0; kt < CIN / BK; ++kt) {
    const int k0 = kt * BK;
    // Store staged tile to LDS (waits on the in-flight loads here).
    if (k0 < C2) {
      As[ks + 0][ar] = w0 * a00.x + w1 * a10.x + w2 * a20.x;
      As[ks + 1][ar] = w0 * a00.y + w1 * a10.y + w2 * a20.y;
      As[ks + 2][ar] = w0 * a00.z + w1 * a10.z + w2 * a20.z;
      As[ks + 3][ar] = w0 * a00.w + w1 * a10.w + w2 * a20.w;
      As[ks + 4][ar] = w0 * a01.x + w1 * a11.x + w2 * a21.x;
      As[ks + 5][ar] = w0 * a01.y + w1 * a11.y + w2 * a21.y;
      As[ks + 6][ar] = w0 * a01.z + w1 * a11.z + w2 * a21.z;
      As[ks + 7][ar] = w0 * a01.w + w1 * a11.w + w2 * a21.w;
    } else {
      As[ks + 0][ar] = a00.x;
      As[ks + 1][ar] = a00.y;
      As[ks + 2][ar] = a00.z;
      As[ks + 3][ar] = a00.w;
      As[ks + 4][ar] = a01.x;
      As[ks + 5][ar] = a01.y;
      As[ks + 6][ar] = a01.z;
      As[ks + 7][ar] = a01.w;
    }
    Bs[bks + 0][bn] = bw0.x;
    Bs[bks + 1][bn] = bw0.y;
    Bs[bks + 2][bn] = bw0.z;
    Bs[bks + 3][bn] = bw0.w;
    Bs[bks + 4][bn] = bw1.x;
    Bs[bks + 5][bn] = bw1.y;
    Bs[bks + 6][bn] = bw1.z;
    Bs[bks + 7][bn] = bw1.w;
    __syncthreads();

    // Issue-early: next tile's global loads, in flight during compute.
    if (kt + 1 < CIN / BK) {
      const int kn = k0 + BK;
      if (kn < C2) {
        a00 = *(const float4*)&p0[kn + ks + 0];
        a01 = *(const float4*)&p0[kn + ks + 4];
        a10 = *(const float4*)&p1[kn + ks + 0];
        a11 = *(const float4*)&p1[kn + ks + 4];
        a20 = *(const float4*)&p2[kn + ks + 0];
        a21 = *(const float4*)&p2[kn + ks + 4];
      } else {
        a00 = *(const float4*)&f1row[kn + ks + 0 - C2];
        a01 = *(const float4*)&f1row[kn + ks + 4 - C2];
      }
      bw0 = *(const float4*)&wbase[kn + bks + 0];
      bw1 = *(const float4*)&wbase[kn + bks + 4];
    }

#pragma unroll
    for (int c = 0; c < BK; ++c) {
      float4 av  = *(const float4*)&As[c][ty * 4];
      float4 bv0 = *(const float4*)&Bs[c][tx * 4];
      float4 bv1 = *(const float4*)&Bs[c][64 + tx * 4];
      float aa[4] = {av.x, av.y, av.z, av.w};
      float bb[8] = {bv0.x, bv0.y, bv0.z, bv0.w, bv1.x, bv1.y, bv1.z, bv1.w};
#pragma unroll
      for (int i = 0; i < 4; ++i)
#pragma unroll
        for (int j = 0; j < 8; ++j) acc[i][j] = fmaf(aa[i], bb[j], acc[i][j]);
    }
    __syncthreads();
  }

  float4 bias0 = *(const float4*)&b1[n0 + tx * 4];
  float4 bias1 = *(const float4*)&b1[n0 + 64 + tx * 4];
#pragma unroll
  for (int i = 0; i < 4; ++i) {
    size_t row = m0 + ty * 4 + i;
    *(float4*)&h1[row * H1 + n0 + tx * 4] =
        make_float4(acc[i][0] + bias0.x, acc[i][1] + bias0.y,
                    acc[i][2] + bias0.z, acc[i][3] + bias0.w);
    *(float4*)&h1[row * H1 + n0 + 64 + tx * 4] =
        make_float4(acc[i][4] + bias1.x, acc[i][5] + bias1.y,
                    acc[i][6] + bias1.z, acc[i][7] + bias1.w);
  }
}

__global__ __launch_bounds__(512) void gemm2_kernel(
    const float* __restrict__ h1, const float* __restrict__ scale1,
    const float* __restrict__ shift1, const float* __restrict__ W2,
    const float* __restrict__ b2, float* __restrict__ h2) {
  __shared__ float As[BK][BM];
  __shared__ float Bs[BK][BN];
  const int t = threadIdx.x;
  const int m0 = blockIdx.x * BM;
  const int n0 = blockIdx.y * BN;
  const int tx = t & 15, ty = t >> 4;

  const int ar = t & 127;
  const int ks = (t >> 7) * 8;
  const size_t arow = m0 + ar;
  const float* hrow = h1 + arow * H1;

  const int bn = t & 127;
  const int bks = (t >> 7) * 8;
  const float* wbase = W2 + (size_t)(n0 + bn) * H1;

  float4 v0, v1, sc0, sc1, sh0, sh1, bw0, bw1;

  v0  = *(const float4*)&hrow[ks + 0];
  v1  = *(const float4*)&hrow[ks + 4];
  sc0 = *(const float4*)&scale1[ks + 0];
  sc1 = *(const float4*)&scale1[ks + 4];
  sh0 = *(const float4*)&shift1[ks + 0];
  sh1 = *(const float4*)&shift1[ks + 4];
  bw0 = *(const float4*)&wbase[bks + 0];
  bw1 = *(const float4*)&wbase[bks + 4];

  float acc[4][8] = {};

  for (int kt = 0; kt < H1 / BK; ++kt) {
    const int k0 = kt * BK;
    As[ks + 0][ar] = fmaxf(fmaf(v0.x, sc0.x, sh0.x), 0.0f);
    As[ks + 1][ar] = fmaxf(fmaf(v0.y, sc0.y, sh0.y), 0.0f);
    As[ks + 2][ar] = fmaxf(fmaf(v0.z, sc0.z, sh0.z), 0.0f);
    As[ks + 3][ar] = fmaxf(fmaf(v0.w, sc0.w, sh0.w), 0.0f);
    As[ks + 4][ar] = fmaxf(fmaf(v1.x, sc1.x, sh1.x), 0.0f);
    As[ks + 5][ar] = fmaxf(fmaf(v1.y, sc1.y, sh1.y), 0.0f);
    As[ks + 6][ar] = fmaxf(fmaf(v1.z, sc1.z, sh1.z), 0.0f);
    As[ks + 7][ar] = fmaxf(fmaf(v1.w, sc1.w, sh1.w), 0.0f);
    Bs[bks + 0][bn] = bw0.x;
    Bs[bks + 1][bn] = bw0.y;
    Bs[bks + 2][bn] = bw0.z;
    Bs[bks + 3][bn] = bw0.w;
    Bs[bks + 4][bn] = bw1.x;
    Bs[bks + 5][bn] = bw1.y;
    Bs[bks + 6][bn] = bw1.z;
    Bs[bks + 7][bn] = bw1.w;
    __syncthreads();

    if (kt + 1 < H1 / BK) {
      const int kn = k0 + BK;
      v0  = *(const float4*)&hrow[kn + ks + 0];
      v1  = *(const float4*)&hrow[kn + ks + 4];
      sc0 = *(const float4*)&scale1[kn + ks + 0];
      sc1 = *(const float4*)&scale1[kn + ks + 4];
      sh0 = *(const float4*)&shift1[kn + ks + 0];
      sh1 = *(const float4*)&shift1[kn + ks + 4];
      bw0 = *(const float4*)&wbase[kn + bks + 0];
      bw1 = *(const float4*)&wbase[kn + bks + 4];
    }

#pragma unroll
    for (int c = 0; c < BK; ++c) {
      float4 av  = *(const float4*)&As[c][ty * 4];
      float4 bv0 = *(const float4*)&Bs[c][tx * 4];
      float4 bv1 = *(const float4*)&Bs[c][64 + tx * 4];
      float aa[4] = {av.x, av.y, av.z, av.w};
      float bb[8] = {bv0.x, bv0.y, bv0.z, bv0.w, bv1.x, bv1.y, bv1.z, bv1.w};
#pragma unroll
      for (int i = 0; i < 4; ++i)
#pragma unroll
        for (int j = 0; j < 8; ++j) acc[i][j] = fmaf(aa[i], bb[j], acc[i][j]);
    }
    __syncthreads();
  }

  float4 bias0 = *(const float4*)&b2[n0 + tx * 4];
  float4 bias1 = *(const float4*)&b2[n0 + 64 + tx * 4];
#pragma unroll
  for (int i = 0; i < 4; ++i) {
    size_t row = m0 + ty * 4 + i;
    *(float4*)&h2[row * H2 + n0 + tx * 4] =
        make_float4(acc[i][0] + bias0.x, acc[i][1] + bias0.y,
                    acc[i][2] + bias0.z, acc[i][3] + bias0.w);
    *(float4*)&h2[row * H2 + n0 + 64 + tx * 4] =
        make_float4(acc[i][4] + bias1.x, acc[i][5] + bias1.y,
                    acc[i][6] + bias1.z, acc[i][7] + bias1.w);
  }
}

// ---------------------------------------------------------------------------
// BN stats, two-stage (no atomics). Partials overlay DEAD storage.
// ---------------------------------------------------------------------------
__global__ __launch_bounds__(256) void colstats_part_kernel(
    const float* __restrict__ h, double* __restrict__ psum,
    double* __restrict__ psq, int C, int logC, int rowsPerBlock) {
  const int t = threadIdx.x;
  const int G = 256 >> logC;       // 1 for C=256, 2 for C=128
  const int c = t & (C - 1);
  const int g = t >> logC;
  const size_t row0 = (size_t)blockIdx.x * rowsPerBlock;
  double s = 0.0, s2 = 0.0;
  for (int r = g; r < rowsPerBlock; r += G) {
    double v = (double)h[(row0 + r) * C + c];
    s += v;
    s2 += v * v;
  }
  const size_t o = (size_t)(blockIdx.x * G + g) * C + c;
  psum[o] = s;
  psq[o] = s2;
}

__global__ __launch_bounds__(256) void colstats_reduce_kernel(
    const double* __restrict__ psum, const double* __restrict__ psq,
    int C, int P, double* __restrict__ sum, double* __restrict__ sumsq) {
  const int t = threadIdx.x;
  const int c = blockIdx.x * 64 + (t & 63);
  const int j = t >> 6;  // 0..3
  double s = 0.0, s2 = 0.0;
  for (int p = j; p < P; p += 4) {
    s += psum[(size_t)p * C + c];
    s2 += psq[(size_t)p * C + c];
  }
  __shared__ double red[2][4][64];
  red[0][j][t & 63] = s;
  red[1][j][t & 63] = s2;
  __syncthreads();
  if (j == 0) {
    double fs = red[0][0][t] + red[0][1][t] + red[0][2][t] + red[0][3][t];
    double fq = red[1][0][t] + red[1][1][t] + red[1][2][t] + red[1][3][t];
    sum[c] = fs;
    sumsq[c] = fq;
  }
}

__global__ void finalize_kernel(const double* __restrict__ sum,
                                const double* __restrict__ sumsq,
                                const float* __restrict__ g,
                                const float* __restrict__ be,
                                float* __restrict__ scale,
                                float* __restrict__ shift) {
  const int c = threadIdx.x;
  const double invM = 1.0 / (double)MROWS;
  double mean = sum[c] * invM;
  double var = sumsq[c] * invM - mean * mean;
  double sc = (double)g[c] / sqrt(var + 1e-5);
  scale[c] = (float)sc;
  shift[c] = (float)((double)be[c] - mean * sc);
}

// In-place: io = relu(io*scale2 + shift2), float4-vectorized.
__global__ __launch_bounds__(256) void final_kernel(
    float* __restrict__ io, const float* __restrict__ scale2,
    const float* __restrict__ shift2) {
  const size_t i = (size_t)blockIdx.x * 256 + threadIdx.x;
  const int col4 = (int)(i & 31);
  float4 h = ((float4*)io)[i];
  float4 sc = ((const float4*)scale2)[col4];
  float4 sh = ((const float4*)shift2)[col4];
  float4 o;
  o.x = fmaxf(fmaf(h.x, sc.x, sh.x), 0.0f);
  o.y = fmaxf(fmaf(h.y, sc.y, sh.y), 0.0f);
  o.z = fmaxf(fmaf(h.z, sc.z, sh.z), 0.0f);
  o.w = fmaxf(fmaf(h.w, sc.w, sh.w), 0.0f);
  ((float4*)io)[i] = o;
}

extern "C" void kernel_launch(void* const* d_in, const int* in_sizes, int n_in,
                              void* d_out, int out_size, void* d_ws,
                              size_t ws_size, hipStream_t stream) {
  const float* xyz1      = (const float*)d_in[0];
  const float* xyz2      = (const float*)d_in[1];
  const float* features1 = (const float*)d_in[2];
  const float* features2 = (const float*)d_in[3];
  const float* W1  = (const float*)d_in[4];
  const float* b1  = (const float*)d_in[5];
  const float* g1  = (const float*)d_in[6];
  const float* be1 = (const float*)d_in[7];
  const float* W2  = (const float*)d_in[8];
  const float* b2  = (const float*)d_in[9];
  const float* g2  = (const float*)d_in[10];
  const float* be2 = (const float*)d_in[11];
  float* out = (float*)d_out;

  // Workspace (~66 MB): h1 | w3 | idx3 | fp64 sums | scale/shift.
  // KNN partials (pd 6.3MB + pi 6.3MB) OVERLAY the h1 region: consumed by
  // knn_merge before gemm1 writes h1.
  char* wsb   = (char*)d_ws;
  float* h1   = (float*)wsb;                               // 64 MB
  float* w3   = (float*)(wsb + (size_t)MROWS * H1 * 4);
  int* idx3   = (int*)(wsb + (size_t)MROWS * H1 * 4 + (size_t)MROWS * 3 * 4);
  double* sums = (double*)((char*)idx3 + (size_t)MROWS * 3 * 4);
  double* sum1 = sums;
  double* sq1s = sums + 256;
  double* sum2 = sums + 512;
  double* sq2s = sums + 640;
  float* ss    = (float*)(sums + 768);
  float* scale1 = ss;
  float* shift1 = ss + 256;
  float* scale2 = ss + 512;
  float* shift2 = ss + 640;

  float* pd = h1;                                  // 6.3 MB overlay
  int*   pi = (int*)(h1 + (size_t)MROWS * NCHUNK * 3);  // next 6.3 MB

  // BN-stats partials overlay dead buffers:
  //  h1 stats (before gemm2 writes out): partials in d_out (4 MB of 32 MB)
  //  out stats (after gemm2, h1 dead):   partials in h1    (4 MB of 64 MB)
  double* psum1 = (double*)out;
  double* psq1  = psum1 + (size_t)1024 * H1;       // P1 = 1024
  double* psum2 = (double*)h1;
  double* psq2  = psum2 + (size_t)2048 * H2;       // P2 = 1024*2 groups

  knn_part_kernel<<<dim3(NPTS / 256, NCHUNK, BATCH), 256, 0, stream>>>(
      xyz1, xyz2, pd, pi);
  knn_merge_kernel<<<MROWS / 256, 256, 0, stream>>>(pd, pi, idx3, w3);
  gemm1_kernel<<<dim3(MROWS / BM, H1 / BN), 512, 0, stream>>>(
      features2, features1, idx3, w3, W1, b1, h1);
  colstats_part_kernel<<<1024, 256, 0, stream>>>(h1, psum1, psq1, H1, 8,
                                                 MROWS / 1024);
  colstats_reduce_kernel<<<H1 / 64, 256, 0, stream>>>(psum1, psq1, H1, 1024,
                                                      sum1, sq1s);
  finalize_kernel<<<1, H1, 0, stream>>>(sum1, sq1s, g1, be1, scale1, shift1);
  gemm2_kernel<<<dim3(MROWS / BM, H2 / BN), 512, 0, stream>>>(h1, scale1, shift1,
                                                              W2, b2, out);
  colstats_part_kernel<<<1024, 256, 0, stream>>>(out, psum2, psq2, H2, 7,
                                                 MROWS / 1024);
  colstats_reduce_kernel<<<H2 / 64, 256, 0, stream>>>(psum2, psq2, H2, 2048,
                                                      sum2, sq2s);
  finalize_kernel<<<1, H2, 0, stream>>>(sum2, sq2s, g2, be2, scale2, shift2);
  final_kernel<<<(MROWS * H2 / 4) / 256, 256, 0, stream>>>(out, scale2, shift2);
}

// Round 5
// 718.809 us; speedup vs baseline: 7.2559x; 1.0865x over previous
//
#include <hip/hip_runtime.h>

#define BATCH 4
#define NPTS  16384
#define SPTS  4096
#define C1    128
#define C2    256
#define CIN   384
#define H1    256
#define H2    128
#define MROWS (BATCH * NPTS)   // 65536

#define CHUNK  512
#define NCHUNK (SPTS / CHUNK)  // 8

// ---------------------------------------------------------------------------
// KNN phase 1: per-chunk top-3. FROZEN ARITHMETIC (verified passing,
// absmax 0.03125).
// ---------------------------------------------------------------------------
__global__ __launch_bounds__(256) void knn_part_kernel(
    const float* __restrict__ xyz1, const float* __restrict__ xyz2,
    float* __restrict__ pd, int* __restrict__ pi) {
#pragma clang fp contract(off)
  __shared__ float4 pts[CHUNK];  // 8 KB
  const int b = blockIdx.z;
  const int chunk = blockIdx.y;
  const int c0 = chunk * CHUNK;
  const float* src = xyz2 + ((size_t)b * SPTS + c0) * 3;
  for (int i = threadIdx.x; i < CHUNK; i += 256) {
    float px = src[i * 3 + 0], py = src[i * 3 + 1], pz = src[i * 3 + 2];
    float s = fmaf(pz, pz, fmaf(px, px, py * py));
    pts[i] = make_float4(px, py, pz, s);
  }
  __syncthreads();

  const int n = blockIdx.x * 256 + threadIdx.x;
  const size_t row = (size_t)b * NPTS + n;
  const float qx = xyz1[row * 3 + 0], qy = xyz1[row * 3 + 1], qz = xyz1[row * 3 + 2];
  const float sq1 = fmaf(qz, qz, fmaf(qx, qx, qy * qy));

  float b0 = 1e30f, b1v = 1e30f, b2v = 1e30f;
  int i0 = 0, i1 = 0, i2 = 0;
  for (int s = 0; s < CHUNK; ++s) {
    float4 p = pts[s];
    float dot = fmaf(qz, p.z, fmaf(qy, p.y, qx * p.x));
    float t1 = sq1 + p.w;
    float d = fmaf(-2.0f, dot, t1);
    if (d < b2v) {
      int gi = c0 + s;
      if (d < b1v) {
        b2v = b1v; i2 = i1;
        if (d < b0) { b1v = b0; i1 = i0; b0 = d; i0 = gi; }
        else        { b1v = d;  i1 = gi; }
      } else { b2v = d; i2 = gi; }
    }
  }
  const size_t o = (row * NCHUNK + chunk) * 3;
  pd[o + 0] = b0;  pd[o + 1] = b1v; pd[o + 2] = b2v;
  pi[o + 0] = i0;  pi[o + 1] = i1;  pi[o + 2] = i2;
}

// ---------------------------------------------------------------------------
// KNN phase 2: merge 8 partial top-3s (frozen).
// ---------------------------------------------------------------------------
__global__ __launch_bounds__(256) void knn_merge_kernel(
    const float* __restrict__ pd, const int* __restrict__ pi,
    int* __restrict__ idx3, float* __restrict__ w3) {
#pragma clang fp contract(off)
  const size_t row = (size_t)blockIdx.x * 256 + threadIdx.x;
  const size_t base = row * (NCHUNK * 3);
  float b0 = 1e30f, b1v = 1e30f, b2v = 1e30f;
  int i0 = 0, i1 = 0, i2 = 0;
#pragma unroll
  for (int k = 0; k < NCHUNK * 3; ++k) {
    float d = pd[base + k];
    int gi = pi[base + k];
    if (d < b2v) {
      if (d < b1v) {
        b2v = b1v; i2 = i1;
        if (d < b0) { b1v = b0; i1 = i0; b0 = d; i0 = gi; }
        else        { b1v = d;  i1 = gi; }
      } else { b2v = d; i2 = gi; }
    }
  }
  float r0 = 1.0f / (b0 + 1e-8f);
  float r1 = 1.0f / (b1v + 1e-8f);
  float r2 = 1.0f / (b2v + 1e-8f);
  float rs = (r0 + r1) + r2;
  idx3[row * 3 + 0] = i0; idx3[row * 3 + 1] = i1; idx3[row * 3 + 2] = i2;
  w3[row * 3 + 0] = r0 / rs;
  w3[row * 3 + 1] = r1 / rs;
  w3[row * 3 + 2] = r2 / rs;
}

// ---------------------------------------------------------------------------
// GEMMs: 128x128 tile, BK=16, 256 threads, 8x8 microtile (R1's verified
// 64-FMA-per-c-step density) + R4's codegen-safe named-register prefetch.
// BK=16 shrinks per-thread staging to 8 named float4 (A-gather 6 + B 2) so
// acc(64)+staging(32)+frags(16) fits ~145 VGPR — no spill, no scratch
// demotion (R2/R4 lessons). 4-wave blocks, ~3 blocks/CU: inter-block
// overlap covers barrier/stage phases. LDS 16 KB, stores 2-way bank (free).
// K-accumulation: c ascending within tile, tiles ascending -> k=0..K-1
// ascending: fmaf chain per output IDENTICAL to all verified rounds.
// ---------------------------------------------------------------------------
#define BM 128
#define BN 128
#define BK 16

__global__ __launch_bounds__(256) void gemm1_kernel(
    const float* __restrict__ features2, const float* __restrict__ features1,
    const int* __restrict__ idx3, const float* __restrict__ w3,
    const float* __restrict__ W1, const float* __restrict__ b1,
    float* __restrict__ h1) {
  __shared__ float As[BK][BM];  // 8 KB
  __shared__ float Bs[BK][BN];  // 8 KB
  const int t = threadIdx.x;
  const int m0 = blockIdx.x * BM;
  const int n0 = blockIdx.y * BN;
  const int tx = t & 15, ty = t >> 4;   // 16x16 compute grid, 8x8 microtile

  const int ar = t & 127;           // A loader: row 0..127
  const int ks = (t >> 7) * 8;      // k-octet 0 or 8
  const size_t arow = m0 + ar;
  const int ab = (int)(arow >> 14);
  const float* f2 = features2 + (size_t)ab * SPTS * C2;
  const float* p0 = f2 + (size_t)idx3[arow * 3 + 0] * C2;
  const float* p1 = f2 + (size_t)idx3[arow * 3 + 1] * C2;
  const float* p2 = f2 + (size_t)idx3[arow * 3 + 2] * C2;
  const float w0 = w3[arow * 3 + 0];
  const float w1 = w3[arow * 3 + 1];
  const float w2 = w3[arow * 3 + 2];
  const float* f1row = features1 + arow * C1;

  const int bn = t & 127;           // B loader: col 0..127
  const int bks = (t >> 7) * 8;
  const float* wbase = W1 + (size_t)(n0 + bn) * CIN;

  // Named staging regs (NOT arrays — keeps them in VGPRs).
  float4 a00, a01, a10, a11, a20, a21, bw0, bw1;

  // Prologue: tile 0 (k0 = 0 < C2).
  a00 = *(const float4*)&p0[ks + 0];
  a01 = *(const float4*)&p0[ks + 4];
  a10 = *(const float4*)&p1[ks + 0];
  a11 = *(const float4*)&p1[ks + 4];
  a20 = *(const float4*)&p2[ks + 0];
  a21 = *(const float4*)&p2[ks + 4];
  bw0 = *(const float4*)&wbase[bks + 0];
  bw1 = *(const float4*)&wbase[bks + 4];

  float acc[8][8] = {};

  for (int kt = 0; kt < CIN / BK; ++kt) {   // 24 tiles
    const int k0 = kt * BK;
    // Store staged tile to LDS (s_waitcnt on the in-flight loads here).
    if (k0 < C2) {
      As[ks + 0][ar] = w0 * a00.x + w1 * a10.x + w2 * a20.x;
      As[ks + 1][ar] = w0 * a00.y + w1 * a10.y + w2 * a20.y;
      As[ks + 2][ar] = w0 * a00.z + w1 * a10.z + w2 * a20.z;
      As[ks + 3][ar] = w0 * a00.w + w1 * a10.w + w2 * a20.w;
      As[ks + 4][ar] = w0 * a01.x + w1 * a11.x + w2 * a21.x;
      As[ks + 5][ar] = w0 * a01.y + w1 * a11.y + w2 * a21.y;
      As[ks + 6][ar] = w0 * a01.z + w1 * a11.z + w2 * a21.z;
      As[ks + 7][ar] = w0 * a01.w + w1 * a11.w + w2 * a21.w;
    } else {
      As[ks + 0][ar] = a00.x;
      As[ks + 1][ar] = a00.y;
      As[ks + 2][ar] = a00.z;
      As[ks + 3][ar] = a00.w;
      As[ks + 4][ar] = a01.x;
      As[ks + 5][ar] = a01.y;
      As[ks + 6][ar] = a01.z;
      As[ks + 7][ar] = a01.w;
    }
    Bs[bks + 0][bn] = bw0.x;
    Bs[bks + 1][bn] = bw0.y;
    Bs[bks + 2][bn] = bw0.z;
    Bs[bks + 3][bn] = bw0.w;
    Bs[bks + 4][bn] = bw1.x;
    Bs[bks + 5][bn] = bw1.y;
    Bs[bks + 6][bn] = bw1.z;
    Bs[bks + 7][bn] = bw1.w;
    __syncthreads();

    // Issue-early: next tile's global loads, in flight during compute.
    if (kt + 1 < CIN / BK) {
      const int kn = k0 + BK;
      if (kn < C2) {
        a00 = *(const float4*)&p0[kn + ks + 0];
        a01 = *(const float4*)&p0[kn + ks + 4];
        a10 = *(const float4*)&p1[kn + ks + 0];
        a11 = *(const float4*)&p1[kn + ks + 4];
        a20 = *(const float4*)&p2[kn + ks + 0];
        a21 = *(const float4*)&p2[kn + ks + 4];
      } else {
        a00 = *(const float4*)&f1row[kn + ks + 0 - C2];
        a01 = *(const float4*)&f1row[kn + ks + 4 - C2];
      }
      bw0 = *(const float4*)&wbase[kn + bks + 0];
      bw1 = *(const float4*)&wbase[kn + bks + 4];
    }

#pragma unroll
    for (int c = 0; c < BK; ++c) {
      float4 av0 = *(const float4*)&As[c][ty * 4];
      float4 av1 = *(const float4*)&As[c][64 + ty * 4];
      float4 bv0 = *(const float4*)&Bs[c][tx * 4];
      float4 bv1 = *(const float4*)&Bs[c][64 + tx * 4];
      float aa[8] = {av0.x, av0.y, av0.z, av0.w, av1.x, av1.y, av1.z, av1.w};
      float bb[8] = {bv0.x, bv0.y, bv0.z, bv0.w, bv1.x, bv1.y, bv1.z, bv1.w};
#pragma unroll
      for (int i = 0; i < 8; ++i)
#pragma unroll
        for (int j = 0; j < 8; ++j) acc[i][j] = fmaf(aa[i], bb[j], acc[i][j]);
    }
    __syncthreads();
  }

  float4 bias0 = *(const float4*)&b1[n0 + tx * 4];
  float4 bias1 = *(const float4*)&b1[n0 + 64 + tx * 4];
#pragma unroll
  for (int i = 0; i < 4; ++i) {
    size_t ra = m0 + ty * 4 + i;
    size_t rb = m0 + 64 + ty * 4 + i;
    *(float4*)&h1[ra * H1 + n0 + tx * 4] =
        make_float4(acc[i][0] + bias0.x, acc[i][1] + bias0.y,
                    acc[i][2] + bias0.z, acc[i][3] + bias0.w);
    *(float4*)&h1[ra * H1 + n0 + 64 + tx * 4] =
        make_float4(acc[i][4] + bias1.x, acc[i][5] + bias1.y,
                    acc[i][6] + bias1.z, acc[i][7] + bias1.w);
    *(float4*)&h1[rb * H1 + n0 + tx * 4] =
        make_float4(acc[4 + i][0] + bias0.x, acc[4 + i][1] + bias0.y,
                    acc[4 + i][2] + bias0.z, acc[4 + i][3] + bias0.w);
    *(float4*)&h1[rb * H1 + n0 + 64 + tx * 4] =
        make_float4(acc[4 + i][4] + bias1.x, acc[4 + i][5] + bias1.y,
                    acc[4 + i][6] + bias1.z, acc[4 + i][7] + bias1.w);
  }
}

__global__ __launch_bounds__(256) void gemm2_kernel(
    const float* __restrict__ h1, const float* __restrict__ scale1,
    const float* __restrict__ shift1, const float* __restrict__ W2,
    const float* __restrict__ b2, float* __restrict__ h2) {
  __shared__ float As[BK][BM];
  __shared__ float Bs[BK][BN];
  const int t = threadIdx.x;
  const int m0 = blockIdx.x * BM;
  const int n0 = blockIdx.y * BN;
  const int tx = t & 15, ty = t >> 4;

  const int ar = t & 127;
  const int ks = (t >> 7) * 8;
  const size_t arow = m0 + ar;
  const float* hrow = h1 + arow * H1;

  const int bn = t & 127;
  const int bks = (t >> 7) * 8;
  const float* wbase = W2 + (size_t)(n0 + bn) * H1;

  float4 v0, v1, sc0, sc1, sh0, sh1, bw0, bw1;

  v0  = *(const float4*)&hrow[ks + 0];
  v1  = *(const float4*)&hrow[ks + 4];
  sc0 = *(const float4*)&scale1[ks + 0];
  sc1 = *(const float4*)&scale1[ks + 4];
  sh0 = *(const float4*)&shift1[ks + 0];
  sh1 = *(const float4*)&shift1[ks + 4];
  bw0 = *(const float4*)&wbase[bks + 0];
  bw1 = *(const float4*)&wbase[bks + 4];

  float acc[8][8] = {};

  for (int kt = 0; kt < H1 / BK; ++kt) {   // 16 tiles
    const int k0 = kt * BK;
    As[ks + 0][ar] = fmaxf(fmaf(v0.x, sc0.x, sh0.x), 0.0f);
    As[ks + 1][ar] = fmaxf(fmaf(v0.y, sc0.y, sh0.y), 0.0f);
    As[ks + 2][ar] = fmaxf(fmaf(v0.z, sc0.z, sh0.z), 0.0f);
    As[ks + 3][ar] = fmaxf(fmaf(v0.w, sc0.w, sh0.w), 0.0f);
    As[ks + 4][ar] = fmaxf(fmaf(v1.x, sc1.x, sh1.x), 0.0f);
    As[ks + 5][ar] = fmaxf(fmaf(v1.y, sc1.y, sh1.y), 0.0f);
    As[ks + 6][ar] = fmaxf(fmaf(v1.z, sc1.z, sh1.z), 0.0f);
    As[ks + 7][ar] = fmaxf(fmaf(v1.w, sc1.w, sh1.w), 0.0f);
    Bs[bks + 0][bn] = bw0.x;
    Bs[bks + 1][bn] = bw0.y;
    Bs[bks + 2][bn] = bw0.z;
    Bs[bks + 3][bn] = bw0.w;
    Bs[bks + 4][bn] = bw1.x;
    Bs[bks + 5][bn] = bw1.y;
    Bs[bks + 6][bn] = bw1.z;
    Bs[bks + 7][bn] = bw1.w;
    __syncthreads();

    if (kt + 1 < H1 / BK) {
      const int kn = k0 + BK;
      v0  = *(const float4*)&hrow[kn + ks + 0];
      v1  = *(const float4*)&hrow[kn + ks + 4];
      sc0 = *(const float4*)&scale1[kn + ks + 0];
      sc1 = *(const float4*)&scale1[kn + ks + 4];
      sh0 = *(const float4*)&shift1[kn + ks + 0];
      sh1 = *(const float4*)&shift1[kn + ks + 4];
      bw0 = *(const float4*)&wbase[kn + bks + 0];
      bw1 = *(const float4*)&wbase[kn + bks + 4];
    }

#pragma unroll
    for (int c = 0; c < BK; ++c) {
      float4 av0 = *(const float4*)&As[c][ty * 4];
      float4 av1 = *(const float4*)&As[c][64 + ty * 4];
      float4 bv0 = *(const float4*)&Bs[c][tx * 4];
      float4 bv1 = *(const float4*)&Bs[c][64 + tx * 4];
      float aa[8] = {av0.x, av0.y, av0.z, av0.w, av1.x, av1.y, av1.z, av1.w};
      float bb[8] = {bv0.x, bv0.y, bv0.z, bv0.w, bv1.x, bv1.y, bv1.z, bv1.w};
#pragma unroll
      for (int i = 0; i < 8; ++i)
#pragma unroll
        for (int j = 0; j < 8; ++j) acc[i][j] = fmaf(aa[i], bb[j], acc[i][j]);
    }
    __syncthreads();
  }

  float4 bias0 = *(const float4*)&b2[n0 + tx * 4];
  float4 bias1 = *(const float4*)&b2[n0 + 64 + tx * 4];
#pragma unroll
  for (int i = 0; i < 4; ++i) {
    size_t ra = m0 + ty * 4 + i;
    size_t rb = m0 + 64 + ty * 4 + i;
    *(float4*)&h2[ra * H2 + n0 + tx * 4] =
        make_float4(acc[i][0] + bias0.x, acc[i][1] + bias0.y,
                    acc[i][2] + bias0.z, acc[i][3] + bias0.w);
    *(float4*)&h2[ra * H2 + n0 + 64 + tx * 4] =
        make_float4(acc[i][4] + bias1.x, acc[i][5] + bias1.y,
                    acc[i][6] + bias1.z, acc[i][7] + bias1.w);
    *(float4*)&h2[rb * H2 + n0 + tx * 4] =
        make_float4(acc[4 + i][0] + bias0.x, acc[4 + i][1] + bias0.y,
                    acc[4 + i][2] + bias0.z, acc[4 + i][3] + bias0.w);
    *(float4*)&h2[rb * H2 + n0 + 64 + tx * 4] =
        make_float4(acc[4 + i][4] + bias1.x, acc[4 + i][5] + bias1.y,
                    acc[4 + i][6] + bias1.z, acc[4 + i][7] + bias1.w);
  }
}

// ---------------------------------------------------------------------------
// BN stats, two-stage (no atomics). Partials overlay DEAD storage.
// ---------------------------------------------------------------------------
__global__ __launch_bounds__(256) void colstats_part_kernel(
    const float* __restrict__ h, double* __restrict__ psum,
    double* __restrict__ psq, int C, int logC, int rowsPerBlock) {
  const int t = threadIdx.x;
  const int G = 256 >> logC;       // 1 for C=256, 2 for C=128
  const int c = t & (C - 1);
  const int g = t >> logC;
  const size_t row0 = (size_t)blockIdx.x * rowsPerBlock;
  double s = 0.0, s2 = 0.0;
  for (int r = g; r < rowsPerBlock; r += G) {
    double v = (double)h[(row0 + r) * C + c];
    s += v;
    s2 += v * v;
  }
  const size_t o = (size_t)(blockIdx.x * G + g) * C + c;
  psum[o] = s;
  psq[o] = s2;
}

__global__ __launch_bounds__(256) void colstats_reduce_kernel(
    const double* __restrict__ psum, const double* __restrict__ psq,
    int C, int P, double* __restrict__ sum, double* __restrict__ sumsq) {
  const int t = threadIdx.x;
  const int c = blockIdx.x * 64 + (t & 63);
  const int j = t >> 6;  // 0..3
  double s = 0.0, s2 = 0.0;
  for (int p = j; p < P; p += 4) {
    s += psum[(size_t)p * C + c];
    s2 += psq[(size_t)p * C + c];
  }
  __shared__ double red[2][4][64];
  red[0][j][t & 63] = s;
  red[1][j][t & 63] = s2;
  __syncthreads();
  if (j == 0) {
    double fs = red[0][0][t] + red[0][1][t] + red[0][2][t] + red[0][3][t];
    double fq = red[1][0][t] + red[1][1][t] + red[1][2][t] + red[1][3][t];
    sum[c] = fs;
    sumsq[c] = fq;
  }
}

__global__ void finalize_kernel(const double* __restrict__ sum,
                                const double* __restrict__ sumsq,
                                const float* __restrict__ g,
                                const float* __restrict__ be,
                                float* __restrict__ scale,
                                float* __restrict__ shift) {
  const int c = threadIdx.x;
  const double invM = 1.0 / (double)MROWS;
  double mean = sum[c] * invM;
  double var = sumsq[c] * invM - mean * mean;
  double sc = (double)g[c] / sqrt(var + 1e-5);
  scale[c] = (float)sc;
  shift[c] = (float)((double)be[c] - mean * sc);
}

// In-place: io = relu(io*scale2 + shift2), float4-vectorized.
__global__ __launch_bounds__(256) void final_kernel(
    float* __restrict__ io, const float* __restrict__ scale2,
    const float* __restrict__ shift2) {
  const size_t i = (size_t)blockIdx.x * 256 + threadIdx.x;
  const int col4 = (int)(i & 31);
  float4 h = ((float4*)io)[i];
  float4 sc = ((const float4*)scale2)[col4];
  float4 sh = ((const float4*)shift2)[col4];
  float4 o;
  o.x = fmaxf(fmaf(h.x, sc.x, sh.x), 0.0f);
  o.y = fmaxf(fmaf(h.y, sc.y, sh.y), 0.0f);
  o.z = fmaxf(fmaf(h.z, sc.z, sh.z), 0.0f);
  o.w = fmaxf(fmaf(h.w, sc.w, sh.w), 0.0f);
  ((float4*)io)[i] = o;
}

extern "C" void kernel_launch(void* const* d_in, const int* in_sizes, int n_in,
                              void* d_out, int out_size, void* d_ws,
                              size_t ws_size, hipStream_t stream) {
  const float* xyz1      = (const float*)d_in[0];
  const float* xyz2      = (const float*)d_in[1];
  const float* features1 = (const float*)d_in[2];
  const float* features2 = (const float*)d_in[3];
  const float* W1  = (const float*)d_in[4];
  const float* b1  = (const float*)d_in[5];
  const float* g1  = (const float*)d_in[6];
  const float* be1 = (const float*)d_in[7];
  const float* W2  = (const float*)d_in[8];
  const float* b2  = (const float*)d_in[9];
  const float* g2  = (const float*)d_in[10];
  const float* be2 = (const float*)d_in[11];
  float* out = (float*)d_out;

  // Workspace (~66 MB): h1 | w3 | idx3 | fp64 sums | scale/shift.
  // KNN partials (pd 6.3MB + pi 6.3MB) OVERLAY the h1 region: consumed by
  // knn_merge before gemm1 writes h1.
  char* wsb   = (char*)d_ws;
  float* h1   = (float*)wsb;                               // 64 MB
  float* w3   = (float*)(wsb + (size_t)MROWS * H1 * 4);
  int* idx3   = (int*)(wsb + (size_t)MROWS * H1 * 4 + (size_t)MROWS * 3 * 4);
  double* sums = (double*)((char*)idx3 + (size_t)MROWS * 3 * 4);
  double* sum1 = sums;
  double* sq1s = sums + 256;
  double* sum2 = sums + 512;
  double* sq2s = sums + 640;
  float* ss    = (float*)(sums + 768);
  float* scale1 = ss;
  float* shift1 = ss + 256;
  float* scale2 = ss + 512;
  float* shift2 = ss + 640;

  float* pd = h1;                                  // 6.3 MB overlay
  int*   pi = (int*)(h1 + (size_t)MROWS * NCHUNK * 3);  // next 6.3 MB

  // BN-stats partials overlay dead buffers:
  //  h1 stats (before gemm2 writes out): partials in d_out (4 MB of 32 MB)
  //  out stats (after gemm2, h1 dead):   partials in h1    (4 MB of 64 MB)
  double* psum1 = (double*)out;
  double* psq1  = psum1 + (size_t)1024 * H1;       // P1 = 1024
  double* psum2 = (double*)h1;
  double* psq2  = psum2 + (size_t)2048 * H2;       // P2 = 1024*2 groups

  knn_part_kernel<<<dim3(NPTS / 256, NCHUNK, BATCH), 256, 0, stream>>>(
      xyz1, xyz2, pd, pi);
  knn_merge_kernel<<<MROWS / 256, 256, 0, stream>>>(pd, pi, idx3, w3);
  gemm1_kernel<<<dim3(MROWS / BM, H1 / BN), 256, 0, stream>>>(
      features2, features1, idx3, w3, W1, b1, h1);
  colstats_part_kernel<<<1024, 256, 0, stream>>>(h1, psum1, psq1, H1, 8,
                                                 MROWS / 1024);
  colstats_reduce_kernel<<<H1 / 64, 256, 0, stream>>>(psum1, psq1, H1, 1024,
                                                      sum1, sq1s);
  finalize_kernel<<<1, H1, 0, stream>>>(sum1, sq1s, g1, be1, scale1, shift1);
  gemm2_kernel<<<dim3(MROWS / BM, H2 / BN), 256, 0, stream>>>(h1, scale1, shift1,
                                                              W2, b2, out);
  colstats_part_kernel<<<1024, 256, 0, stream>>>(out, psum2, psq2, H2, 7,
                                                 MROWS / 1024);
  colstats_reduce_kernel<<<H2 / 64, 256, 0, stream>>>(psum2, psq2, H2, 2048,
                                                      sum2, sq2s);
  finalize_kernel<<<1, H2, 0, stream>>>(sum2, sq2s, g2, be2, scale2, shift2);
  final_kernel<<<(MROWS * H2 / 4) / 256, 256, 0, stream>>>(out, scale2, shift2);
}

// Round 6
// 498.116 us; speedup vs baseline: 10.4706x; 1.4431x over previous
//
#include <hip/hip_runtime.h>

#define BATCH 4
#define NPTS  16384
#define SPTS  4096
#define C1    128
#define C2    256
#define CIN   384
#define H1    256
#define H2    128
#define MROWS (BATCH * NPTS)   // 65536

#define CHUNK  512
#define NCHUNK (SPTS / CHUNK)  // 8

// ---------------------------------------------------------------------------
// KNN phase 1: per-chunk top-3. FROZEN ARITHMETIC (verified passing,
// absmax 0.03125).
// ---------------------------------------------------------------------------
__global__ __launch_bounds__(256) void knn_part_kernel(
    const float* __restrict__ xyz1, const float* __restrict__ xyz2,
    float* __restrict__ pd, int* __restrict__ pi) {
#pragma clang fp contract(off)
  __shared__ float4 pts[CHUNK];  // 8 KB
  const int b = blockIdx.z;
  const int chunk = blockIdx.y;
  const int c0 = chunk * CHUNK;
  const float* src = xyz2 + ((size_t)b * SPTS + c0) * 3;
  for (int i = threadIdx.x; i < CHUNK; i += 256) {
    float px = src[i * 3 + 0], py = src[i * 3 + 1], pz = src[i * 3 + 2];
    float s = fmaf(pz, pz, fmaf(px, px, py * py));
    pts[i] = make_float4(px, py, pz, s);
  }
  __syncthreads();

  const int n = blockIdx.x * 256 + threadIdx.x;
  const size_t row = (size_t)b * NPTS + n;
  const float qx = xyz1[row * 3 + 0], qy = xyz1[row * 3 + 1], qz = xyz1[row * 3 + 2];
  const float sq1 = fmaf(qz, qz, fmaf(qx, qx, qy * qy));

  float b0 = 1e30f, b1v = 1e30f, b2v = 1e30f;
  int i0 = 0, i1 = 0, i2 = 0;
  for (int s = 0; s < CHUNK; ++s) {
    float4 p = pts[s];
    float dot = fmaf(qz, p.z, fmaf(qy, p.y, qx * p.x));
    float t1 = sq1 + p.w;
    float d = fmaf(-2.0f, dot, t1);
    if (d < b2v) {
      int gi = c0 + s;
      if (d < b1v) {
        b2v = b1v; i2 = i1;
        if (d < b0) { b1v = b0; i1 = i0; b0 = d; i0 = gi; }
        else        { b1v = d;  i1 = gi; }
      } else { b2v = d; i2 = gi; }
    }
  }
  const size_t o = (row * NCHUNK + chunk) * 3;
  pd[o + 0] = b0;  pd[o + 1] = b1v; pd[o + 2] = b2v;
  pi[o + 0] = i0;  pi[o + 1] = i1;  pi[o + 2] = i2;
}

// ---------------------------------------------------------------------------
// KNN phase 2: merge 8 partial top-3s (frozen).
// ---------------------------------------------------------------------------
__global__ __launch_bounds__(256) void knn_merge_kernel(
    const float* __restrict__ pd, const int* __restrict__ pi,
    int* __restrict__ idx3, float* __restrict__ w3) {
#pragma clang fp contract(off)
  const size_t row = (size_t)blockIdx.x * 256 + threadIdx.x;
  const size_t base = row * (NCHUNK * 3);
  float b0 = 1e30f, b1v = 1e30f, b2v = 1e30f;
  int i0 = 0, i1 = 0, i2 = 0;
#pragma unroll
  for (int k = 0; k < NCHUNK * 3; ++k) {
    float d = pd[base + k];
    int gi = pi[base + k];
    if (d < b2v) {
      if (d < b1v) {
        b2v = b1v; i2 = i1;
        if (d < b0) { b1v = b0; i1 = i0; b0 = d; i0 = gi; }
        else        { b1v = d;  i1 = gi; }
      } else { b2v = d; i2 = gi; }
    }
  }
  float r0 = 1.0f / (b0 + 1e-8f);
  float r1 = 1.0f / (b1v + 1e-8f);
  float r2 = 1.0f / (b2v + 1e-8f);
  float rs = (r0 + r1) + r2;
  idx3[row * 3 + 0] = i0; idx3[row * 3 + 1] = i1; idx3[row * 3 + 2] = i2;
  w3[row * 3 + 0] = r0 / rs;
  w3[row * 3 + 1] = r1 / rs;
  w3[row * 3 + 2] = r2 / rs;
}

// ---------------------------------------------------------------------------
// GEMMs: EXACT round-1 structure (best measured: 183 us gemm1) — 128x128
// tile, BK=32, 256 threads, 8x8 microtile, single-buffer LDS, two barriers
// per tile, NO prefetch (every pipelining variant measured slower: R2 spill,
// R3 scratch, R4 low-density, R5 barrier-doubling).
// NEW: BN column-stat partials fused into the epilogue — fp32 per-thread
// sum/sumsq of the 8x8 written values, shfl_xor(16/32) ty-reduce, 4 KB LDS
// cross-wave reduce, one non-atomic [block][col] partial store. Removes the
// 64MB + 32MB colstats re-read passes. Stored outputs are byte-identical;
// stats order changes are proven tolerant (R1->R2 transition).
// ---------------------------------------------------------------------------
#define BM 128
#define BN 128
#define BK 32

__global__ __launch_bounds__(256) void gemm1_kernel(
    const float* __restrict__ features2, const float* __restrict__ features1,
    const int* __restrict__ idx3, const float* __restrict__ w3,
    const float* __restrict__ W1, const float* __restrict__ b1,
    float* __restrict__ h1, float* __restrict__ psum,
    float* __restrict__ psq) {
  __shared__ float As[BK][BM];         // 16 KB
  __shared__ float Bs[BK][BN];         // 16 KB
  __shared__ float redsm[2][4][128];   // 4 KB (epilogue stats)
  const int t = threadIdx.x;
  const int m0 = blockIdx.x * BM;
  const int n0 = blockIdx.y * BN;
  const int tx = t & 15, ty = t >> 4;   // 16x16 thread grid

  // A loader: each thread loads one row-half (16 consecutive k) of the tile.
  const int ar = t >> 1;           // 0..127
  const int kq = (t & 1) * 16;     // 0 or 16
  const size_t arow = m0 + ar;
  const int ab = (int)(arow >> 14);
  const float* f2 = features2 + (size_t)ab * SPTS * C2;
  const size_t r0i = (size_t)idx3[arow * 3 + 0] * C2;
  const size_t r1i = (size_t)idx3[arow * 3 + 1] * C2;
  const size_t r2i = (size_t)idx3[arow * 3 + 2] * C2;
  const float w0 = w3[arow * 3 + 0];
  const float w1 = w3[arow * 3 + 1];
  const float w2 = w3[arow * 3 + 2];
  const float* f1row = features1 + arow * C1;

  float acc[8][8] = {};

  for (int k0 = 0; k0 < CIN; k0 += BK) {
    if (k0 < C2) {
#pragma unroll
      for (int q = 0; q < 4; ++q) {
        int col = k0 + kq + q * 4;
        float4 x0 = *(const float4*)&f2[r0i + col];
        float4 x1 = *(const float4*)&f2[r1i + col];
        float4 x2 = *(const float4*)&f2[r2i + col];
        As[kq + q * 4 + 0][ar] = w0 * x0.x + w1 * x1.x + w2 * x2.x;
        As[kq + q * 4 + 1][ar] = w0 * x0.y + w1 * x1.y + w2 * x2.y;
        As[kq + q * 4 + 2][ar] = w0 * x0.z + w1 * x1.z + w2 * x2.z;
        As[kq + q * 4 + 3][ar] = w0 * x0.w + w1 * x1.w + w2 * x2.w;
      }
    } else {
#pragma unroll
      for (int q = 0; q < 4; ++q) {
        int col = k0 + kq + q * 4 - C2;
        float4 x = *(const float4*)&f1row[col];
        As[kq + q * 4 + 0][ar] = x.x;
        As[kq + q * 4 + 1][ar] = x.y;
        As[kq + q * 4 + 2][ar] = x.z;
        As[kq + q * 4 + 3][ar] = x.w;
      }
    }
    {
      const int bn = t >> 1;
      const int bkq = (t & 1) * 16;
      const float* wrow = W1 + (size_t)(n0 + bn) * CIN + k0;
#pragma unroll
      for (int q = 0; q < 4; ++q) {
        float4 wv = *(const float4*)&wrow[bkq + q * 4];
        Bs[bkq + q * 4 + 0][bn] = wv.x;
        Bs[bkq + q * 4 + 1][bn] = wv.y;
        Bs[bkq + q * 4 + 2][bn] = wv.z;
        Bs[bkq + q * 4 + 3][bn] = wv.w;
      }
    }
    __syncthreads();
#pragma unroll
    for (int c = 0; c < BK; ++c) {
      float4 av0 = *(const float4*)&As[c][ty * 4];
      float4 av1 = *(const float4*)&As[c][64 + ty * 4];
      float4 bv0 = *(const float4*)&Bs[c][tx * 4];
      float4 bv1 = *(const float4*)&Bs[c][64 + tx * 4];
      float aa[8] = {av0.x, av0.y, av0.z, av0.w, av1.x, av1.y, av1.z, av1.w};
      float bb[8] = {bv0.x, bv0.y, bv0.z, bv0.w, bv1.x, bv1.y, bv1.z, bv1.w};
#pragma unroll
      for (int i = 0; i < 8; ++i)
#pragma unroll
        for (int j = 0; j < 8; ++j) acc[i][j] = fmaf(aa[i], bb[j], acc[i][j]);
    }
    __syncthreads();
  }
  float4 bias0 = *(const float4*)&b1[n0 + tx * 4];
  float4 bias1 = *(const float4*)&b1[n0 + 64 + tx * 4];
#pragma unroll
  for (int i = 0; i < 4; ++i) {
    size_t ra = m0 + ty * 4 + i;
    size_t rb = m0 + 64 + ty * 4 + i;
    *(float4*)&h1[ra * H1 + n0 + tx * 4] =
        make_float4(acc[i][0] + bias0.x, acc[i][1] + bias0.y,
                    acc[i][2] + bias0.z, acc[i][3] + bias0.w);
    *(float4*)&h1[ra * H1 + n0 + 64 + tx * 4] =
        make_float4(acc[i][4] + bias1.x, acc[i][5] + bias1.y,
                    acc[i][6] + bias1.z, acc[i][7] + bias1.w);
    *(float4*)&h1[rb * H1 + n0 + tx * 4] =
        make_float4(acc[4 + i][0] + bias0.x, acc[4 + i][1] + bias0.y,
                    acc[4 + i][2] + bias0.z, acc[4 + i][3] + bias0.w);
    *(float4*)&h1[rb * H1 + n0 + 64 + tx * 4] =
        make_float4(acc[4 + i][4] + bias1.x, acc[4 + i][5] + bias1.y,
                    acc[4 + i][6] + bias1.z, acc[4 + i][7] + bias1.w);
  }

  // -------- fused column-stat partials (values == stored floats) ----------
  float bb8[8] = {bias0.x, bias0.y, bias0.z, bias0.w,
                  bias1.x, bias1.y, bias1.z, bias1.w};
  float cs[8], cq[8];
#pragma unroll
  for (int j = 0; j < 8; ++j) { cs[j] = 0.0f; cq[j] = 0.0f; }
#pragma unroll
  for (int i = 0; i < 8; ++i) {
#pragma unroll
    for (int j = 0; j < 8; ++j) {
      float v = acc[i][j] + bb8[j];
      cs[j] += v;
      cq[j] = fmaf(v, v, cq[j]);
    }
  }
#pragma unroll
  for (int j = 0; j < 8; ++j) {
    cs[j] += __shfl_xor(cs[j], 16);
    cs[j] += __shfl_xor(cs[j], 32);
    cq[j] += __shfl_xor(cq[j], 16);
    cq[j] += __shfl_xor(cq[j], 32);
  }
  const int wv = t >> 6;  // wave 0..3
  if ((t & 63) < 16) {
#pragma unroll
    for (int j = 0; j < 8; ++j) {
      int col = (j < 4) ? (tx * 4 + j) : (64 + tx * 4 + (j - 4));
      redsm[0][wv][col] = cs[j];
      redsm[1][wv][col] = cq[j];
    }
  }
  __syncthreads();
  if (t < 128) {
    float fs = redsm[0][0][t] + redsm[0][1][t] + redsm[0][2][t] + redsm[0][3][t];
    float fq = redsm[1][0][t] + redsm[1][1][t] + redsm[1][2][t] + redsm[1][3][t];
    psum[(size_t)blockIdx.x * H1 + n0 + t] = fs;
    psq[(size_t)blockIdx.x * H1 + n0 + t] = fq;
  }
}

__global__ __launch_bounds__(256) void gemm2_kernel(
    const float* __restrict__ h1, const float* __restrict__ scale1,
    const float* __restrict__ shift1, const float* __restrict__ W2,
    const float* __restrict__ b2, float* __restrict__ h2,
    float* __restrict__ psum, float* __restrict__ psq) {
  __shared__ float As[BK][BM];
  __shared__ float Bs[BK][BN];
  __shared__ float redsm[2][4][128];
  const int t = threadIdx.x;
  const int m0 = blockIdx.x * BM;
  const int n0 = blockIdx.y * BN;
  const int tx = t & 15, ty = t >> 4;

  const int ar = t >> 1;
  const int kq = (t & 1) * 16;
  const size_t arow = m0 + ar;
  const float* hrow = h1 + arow * H1;

  float acc[8][8] = {};

  for (int k0 = 0; k0 < H1; k0 += BK) {
#pragma unroll
    for (int q = 0; q < 4; ++q) {
      int col = k0 + kq + q * 4;
      float4 v = *(const float4*)&hrow[col];
      float4 sc = *(const float4*)&scale1[col];
      float4 sh = *(const float4*)&shift1[col];
      As[kq + q * 4 + 0][ar] = fmaxf(fmaf(v.x, sc.x, sh.x), 0.0f);
      As[kq + q * 4 + 1][ar] = fmaxf(fmaf(v.y, sc.y, sh.y), 0.0f);
      As[kq + q * 4 + 2][ar] = fmaxf(fmaf(v.z, sc.z, sh.z), 0.0f);
      As[kq + q * 4 + 3][ar] = fmaxf(fmaf(v.w, sc.w, sh.w), 0.0f);
    }
    {
      const int bn = t >> 1;
      const int bkq = (t & 1) * 16;
      const float* wrow = W2 + (size_t)(n0 + bn) * H1 + k0;
#pragma unroll
      for (int q = 0; q < 4; ++q) {
        float4 wv = *(const float4*)&wrow[bkq + q * 4];
        Bs[bkq + q * 4 + 0][bn] = wv.x;
        Bs[bkq + q * 4 + 1][bn] = wv.y;
        Bs[bkq + q * 4 + 2][bn] = wv.z;
        Bs[bkq + q * 4 + 3][bn] = wv.w;
      }
    }
    __syncthreads();
#pragma unroll
    for (int c = 0; c < BK; ++c) {
      float4 av0 = *(const float4*)&As[c][ty * 4];
      float4 av1 = *(const float4*)&As[c][64 + ty * 4];
      float4 bv0 = *(const float4*)&Bs[c][tx * 4];
      float4 bv1 = *(const float4*)&Bs[c][64 + tx * 4];
      float aa[8] = {av0.x, av0.y, av0.z, av0.w, av1.x, av1.y, av1.z, av1.w};
      float bb[8] = {bv0.x, bv0.y, bv0.z, bv0.w, bv1.x, bv1.y, bv1.z, bv1.w};
#pragma unroll
      for (int i = 0; i < 8; ++i)
#pragma unroll
        for (int j = 0; j < 8; ++j) acc[i][j] = fmaf(aa[i], bb[j], acc[i][j]);
    }
    __syncthreads();
  }
  float4 bias0 = *(const float4*)&b2[n0 + tx * 4];
  float4 bias1 = *(const float4*)&b2[n0 + 64 + tx * 4];
#pragma unroll
  for (int i = 0; i < 4; ++i) {
    size_t ra = m0 + ty * 4 + i;
    size_t rb = m0 + 64 + ty * 4 + i;
    *(float4*)&h2[ra * H2 + n0 + tx * 4] =
        make_float4(acc[i][0] + bias0.x, acc[i][1] + bias0.y,
                    acc[i][2] + bias0.z, acc[i][3] + bias0.w);
    *(float4*)&h2[ra * H2 + n0 + 64 + tx * 4] =
        make_float4(acc[i][4] + bias1.x, acc[i][5] + bias1.y,
                    acc[i][6] + bias1.z, acc[i][7] + bias1.w);
    *(float4*)&h2[rb * H2 + n0 + tx * 4] =
        make_float4(acc[4 + i][0] + bias0.x, acc[4 + i][1] + bias0.y,
                    acc[4 + i][2] + bias0.z, acc[4 + i][3] + bias0.w);
    *(float4*)&h2[rb * H2 + n0 + 64 + tx * 4] =
        make_float4(acc[4 + i][4] + bias1.x, acc[4 + i][5] + bias1.y,
                    acc[4 + i][6] + bias1.z, acc[4 + i][7] + bias1.w);
  }

  // -------- fused column-stat partials ----------
  float bb8[8] = {bias0.x, bias0.y, bias0.z, bias0.w,
                  bias1.x, bias1.y, bias1.z, bias1.w};
  float cs[8], cq[8];
#pragma unroll
  for (int j = 0; j < 8; ++j) { cs[j] = 0.0f; cq[j] = 0.0f; }
#pragma unroll
  for (int i = 0; i < 8; ++i) {
#pragma unroll
    for (int j = 0; j < 8; ++j) {
      float v = acc[i][j] + bb8[j];
      cs[j] += v;
      cq[j] = fmaf(v, v, cq[j]);
    }
  }
#pragma unroll
  for (int j = 0; j < 8; ++j) {
    cs[j] += __shfl_xor(cs[j], 16);
    cs[j] += __shfl_xor(cs[j], 32);
    cq[j] += __shfl_xor(cq[j], 16);
    cq[j] += __shfl_xor(cq[j], 32);
  }
  const int wv = t >> 6;
  if ((t & 63) < 16) {
#pragma unroll
    for (int j = 0; j < 8; ++j) {
      int col = (j < 4) ? (tx * 4 + j) : (64 + tx * 4 + (j - 4));
      redsm[0][wv][col] = cs[j];
      redsm[1][wv][col] = cq[j];
    }
  }
  __syncthreads();
  if (t < 128) {
    float fs = redsm[0][0][t] + redsm[0][1][t] + redsm[0][2][t] + redsm[0][3][t];
    float fq = redsm[1][0][t] + redsm[1][1][t] + redsm[1][2][t] + redsm[1][3][t];
    psum[(size_t)blockIdx.x * H2 + n0 + t] = fs;
    psq[(size_t)blockIdx.x * H2 + n0 + t] = fq;
  }
}

// ---------------------------------------------------------------------------
// Reduce fp32 block-partials (P x C) into fp64 per-column sum/sumsq.
// ---------------------------------------------------------------------------
__global__ __launch_bounds__(256) void colstats_reduce_f32(
    const float* __restrict__ psum, const float* __restrict__ psq,
    int C, int P, double* __restrict__ sum, double* __restrict__ sumsq) {
  const int t = threadIdx.x;
  const int c = blockIdx.x * 64 + (t & 63);
  const int j = t >> 6;  // 0..3
  double s = 0.0, s2 = 0.0;
  for (int p = j; p < P; p += 4) {
    s += (double)psum[(size_t)p * C + c];
    s2 += (double)psq[(size_t)p * C + c];
  }
  __shared__ double red[2][4][64];
  red[0][j][t & 63] = s;
  red[1][j][t & 63] = s2;
  __syncthreads();
  if (j == 0) {
    double fs = red[0][0][t] + red[0][1][t] + red[0][2][t] + red[0][3][t];
    double fq = red[1][0][t] + red[1][1][t] + red[1][2][t] + red[1][3][t];
    sum[c] = fs;
    sumsq[c] = fq;
  }
}

__global__ void finalize_kernel(const double* __restrict__ sum,
                                const double* __restrict__ sumsq,
                                const float* __restrict__ g,
                                const float* __restrict__ be,
                                float* __restrict__ scale,
                                float* __restrict__ shift) {
  const int c = threadIdx.x;
  const double invM = 1.0 / (double)MROWS;
  double mean = sum[c] * invM;
  double var = sumsq[c] * invM - mean * mean;
  double sc = (double)g[c] / sqrt(var + 1e-5);
  scale[c] = (float)sc;
  shift[c] = (float)((double)be[c] - mean * sc);
}

// In-place: io = relu(io*scale2 + shift2), float4-vectorized.
__global__ __launch_bounds__(256) void final_kernel(
    float* __restrict__ io, const float* __restrict__ scale2,
    const float* __restrict__ shift2) {
  const size_t i = (size_t)blockIdx.x * 256 + threadIdx.x;
  const int col4 = (int)(i & 31);
  float4 h = ((float4*)io)[i];
  float4 sc = ((const float4*)scale2)[col4];
  float4 sh = ((const float4*)shift2)[col4];
  float4 o;
  o.x = fmaxf(fmaf(h.x, sc.x, sh.x), 0.0f);
  o.y = fmaxf(fmaf(h.y, sc.y, sh.y), 0.0f);
  o.z = fmaxf(fmaf(h.z, sc.z, sh.z), 0.0f);
  o.w = fmaxf(fmaf(h.w, sc.w, sh.w), 0.0f);
  ((float4*)io)[i] = o;
}

extern "C" void kernel_launch(void* const* d_in, const int* in_sizes, int n_in,
                              void* d_out, int out_size, void* d_ws,
                              size_t ws_size, hipStream_t stream) {
  const float* xyz1      = (const float*)d_in[0];
  const float* xyz2      = (const float*)d_in[1];
  const float* features1 = (const float*)d_in[2];
  const float* features2 = (const float*)d_in[3];
  const float* W1  = (const float*)d_in[4];
  const float* b1  = (const float*)d_in[5];
  const float* g1  = (const float*)d_in[6];
  const float* be1 = (const float*)d_in[7];
  const float* W2  = (const float*)d_in[8];
  const float* b2  = (const float*)d_in[9];
  const float* g2  = (const float*)d_in[10];
  const float* be2 = (const float*)d_in[11];
  float* out = (float*)d_out;

  // Workspace (~66 MB): h1 | w3 | idx3 | fp64 sums | scale/shift.
  // KNN partials (pd 6.3MB + pi 6.3MB) OVERLAY the h1 region: consumed by
  // knn_merge before gemm1 writes h1.
  char* wsb   = (char*)d_ws;
  float* h1   = (float*)wsb;                               // 64 MB
  float* w3   = (float*)(wsb + (size_t)MROWS * H1 * 4);
  int* idx3   = (int*)(wsb + (size_t)MROWS * H1 * 4 + (size_t)MROWS * 3 * 4);
  double* sums = (double*)((char*)idx3 + (size_t)MROWS * 3 * 4);
  double* sum1 = sums;
  double* sq1s = sums + 256;
  double* sum2 = sums + 512;
  double* sq2s = sums + 640;
  float* ss    = (float*)(sums + 768);
  float* scale1 = ss;
  float* shift1 = ss + 256;
  float* scale2 = ss + 512;
  float* shift2 = ss + 640;

  float* pd = h1;                                  // 6.3 MB overlay
  int*   pi = (int*)(h1 + (size_t)MROWS * NCHUNK * 3);  // next 6.3 MB

  // Fused-stats partial buffers overlay DEAD storage:
  //  gemm1 partials (512 x 256 fp32, x2): in d_out (dead until gemm2 writes)
  //  gemm2 partials (512 x 128 fp32, x2): in w3/idx3 region (dead after gemm1)
  float* psum1 = (float*)out;
  float* psq1  = psum1 + (size_t)512 * H1;
  float* psum2 = w3;
  float* psq2  = psum2 + (size_t)512 * H2;

  knn_part_kernel<<<dim3(NPTS / 256, NCHUNK, BATCH), 256, 0, stream>>>(
      xyz1, xyz2, pd, pi);
  knn_merge_kernel<<<MROWS / 256, 256, 0, stream>>>(pd, pi, idx3, w3);
  gemm1_kernel<<<dim3(MROWS / BM, H1 / BN), 256, 0, stream>>>(
      features2, features1, idx3, w3, W1, b1, h1, psum1, psq1);
  colstats_reduce_f32<<<H1 / 64, 256, 0, stream>>>(psum1, psq1, H1,
                                                   MROWS / BM, sum1, sq1s);
  finalize_kernel<<<1, H1, 0, stream>>>(sum1, sq1s, g1, be1, scale1, shift1);
  gemm2_kernel<<<dim3(MROWS / BM, H2 / BN), 256, 0, stream>>>(
      h1, scale1, shift1, W2, b2, out, psum2, psq2);
  colstats_reduce_f32<<<H2 / 64, 256, 0, stream>>>(psum2, psq2, H2,
                                                   MROWS / BM, sum2, sq2s);
  finalize_kernel<<<1, H2, 0, stream>>>(sum2, sq2s, g2, be2, scale2, shift2);
  final_kernel<<<(MROWS * H2 / 4) / 256, 256, 0, stream>>>(out, scale2, shift2);
}